// Round 2
// baseline (56.344 us; speedup 1.0000x reference)
//
#include <hip/hip_runtime.h>
#include <hip/hip_bf16.h>

#define B_   2
#define L_   1024
#define D_   1024
#define H_   8
#define DV_  1536
#define HDV_ 12288          // H_*DV_
#define INV_L (1.0f/1024.0f)

// ws layout (floats):
//   part : [0, 65536)        2*32*1024 partial column sums of v
//   vsum : [65536, 67584)    2*1024
//   S    : [67584, 92160)    2*12288   per-(b, h*DV+d) column-sum of vh
//   G    : [92160, 96256)    4*1024    order: b0p0, b0p1, b1p0, b1p1

// ---- 1. partial column sums of v -------------------------------------------
__global__ void __launch_bounds__(256) k_vsum_partial(const float* __restrict__ v,
                                                      float* __restrict__ part) {
    int c   = blockIdx.x * 256 + threadIdx.x;   // column 0..1023
    int kch = blockIdx.y;                       // 0..31 (32 rows each)
    int b   = blockIdx.z;
    const float* vp = v + ((size_t)b * L_ + (size_t)kch * 32) * D_ + c;
    float s = 0.f;
    #pragma unroll
    for (int k = 0; k < 32; ++k) s += vp[(size_t)k * D_];
    part[((size_t)b * 32 + kch) * D_ + c] = s;
}

__global__ void __launch_bounds__(256) k_vsum_reduce(const float* __restrict__ part,
                                                     float* __restrict__ vsum) {
    int idx = blockIdx.x * 256 + threadIdx.x;   // 0..2047
    int b = idx >> 10, c = idx & 1023;
    float s = 0.f;
    #pragma unroll
    for (int kch = 0; kch < 32; ++kch) s += part[((size_t)b * 32 + kch) * D_ + c];
    vsum[idx] = s;
}

// ---- 2. S[b,m] = vsum[b,:] . w_vs_w[m,:] + L*b_vs[m]  (one wave per m) -----
__global__ void __launch_bounds__(256) k_vproj(const float* __restrict__ vsum,
                                               const float* __restrict__ wv,
                                               const float* __restrict__ bv,
                                               float* __restrict__ S) {
    int gid  = blockIdx.x * 256 + threadIdx.x;
    int m    = gid >> 6;
    int lane = threadIdx.x & 63;
    if (m >= HDV_) return;
    const float4* row = (const float4*)(wv + (size_t)m * D_);
    const float4* v0  = (const float4*)vsum;
    const float4* v1  = (const float4*)(vsum + D_);
    float a0 = 0.f, a1 = 0.f;
    #pragma unroll
    for (int t = lane; t < D_ / 4; t += 64) {   // 4 iters
        float4 w4 = row[t];
        float4 s0 = v0[t];
        float4 s1 = v1[t];
        a0 += w4.x*s0.x + w4.y*s0.y + w4.z*s0.z + w4.w*s0.w;
        a1 += w4.x*s1.x + w4.y*s1.y + w4.z*s1.z + w4.w*s1.w;
    }
    #pragma unroll
    for (int off = 32; off; off >>= 1) {
        a0 += __shfl_down(a0, off);
        a1 += __shfl_down(a1, off);
    }
    if (lane == 0) {
        float bb = bv[m] * (float)L_;
        S[m]        = a0 + bb;
        S[HDV_ + m] = a1 + bb;
    }
}

// ---- 3. G[b,p,j] = sum_{h%2==p} sum_d S[b,h*DV+d]*fc_w[j,h*DV+d] -----------
__global__ void __launch_bounds__(256) k_fc(const float* __restrict__ S,
                                            const float* __restrict__ fcw,
                                            float* __restrict__ G) {
    int gid  = blockIdx.x * 256 + threadIdx.x;
    int j    = gid >> 6;
    int lane = threadIdx.x & 63;
    if (j >= D_) return;
    const float4* row = (const float4*)(fcw + (size_t)j * HDV_);
    const float4* S0  = (const float4*)S;
    const float4* S1  = (const float4*)(S + HDV_);
    float g00 = 0.f, g01 = 0.f, g10 = 0.f, g11 = 0.f;
    for (int t = lane; t < HDV_ / 4; t += 64) {  // 48 iters
        int p = (t / 384) & 1;                   // 384 = DV_/4; float4 never straddles a head
        float4 w4 = row[t];
        float4 s0 = S0[t];
        float4 s1 = S1[t];
        float d0 = w4.x*s0.x + w4.y*s0.y + w4.z*s0.z + w4.w*s0.w;
        float d1 = w4.x*s1.x + w4.y*s1.y + w4.z*s1.z + w4.w*s1.w;
        if (p) { g01 += d0; g11 += d1; } else { g00 += d0; g10 += d1; }
    }
    #pragma unroll
    for (int off = 32; off; off >>= 1) {
        g00 += __shfl_down(g00, off);
        g01 += __shfl_down(g01, off);
        g10 += __shfl_down(g10, off);
        g11 += __shfl_down(g11, off);
    }
    if (lane == 0) {
        G[j]          = g00;   // b0 p0
        G[D_ + j]     = g01;   // b0 p1
        G[2 * D_ + j] = g10;   // b1 p0
        G[3 * D_ + j] = g11;   // b1 p1
    }
}

// ---- 4. out = LayerNorm(q + (m0*G[b,0] + m1*G[b,1]) / L) -------------------
__global__ void __launch_bounds__(256) k_ln(const float* __restrict__ qin,
                                            const int* __restrict__ mask,
                                            const float* __restrict__ G,
                                            const float* __restrict__ lns,
                                            const float* __restrict__ lnb,
                                            float* __restrict__ out) {
    __shared__ float red[8];
    int row = blockIdx.x;            // b*L + q
    int b   = row >> 10;
    int qi  = row & 1023;
    float m0 = (mask[qi]      != 0) ? INV_L : 0.f;  // mask batch 0 (parity-0 heads)
    float m1 = (mask[L_ + qi] != 0) ? INV_L : 0.f;  // mask batch 1 (parity-1 heads)
    const float4* q4 = (const float4*)(qin + (size_t)row * D_);
    const float4* g0 = (const float4*)(G + (size_t)(2 * b) * D_);
    const float4* g1 = (const float4*)(G + (size_t)(2 * b + 1) * D_);
    int t = threadIdx.x;
    float4 a = q4[t], u = g0[t], w = g1[t];
    float4 x;
    x.x = a.x + m0 * u.x + m1 * w.x;
    x.y = a.y + m0 * u.y + m1 * w.y;
    x.z = a.z + m0 * u.z + m1 * w.z;
    x.w = a.w + m0 * u.w + m1 * w.w;
    float s  = x.x + x.y + x.z + x.w;
    float ss = x.x*x.x + x.y*x.y + x.z*x.z + x.w*x.w;
    #pragma unroll
    for (int off = 32; off; off >>= 1) {
        s  += __shfl_down(s, off);
        ss += __shfl_down(ss, off);
    }
    int lane = t & 63, wv = t >> 6;
    if (lane == 0) { red[wv] = s; red[4 + wv] = ss; }
    __syncthreads();
    if (t == 0) {
        float sAll  = red[0] + red[1] + red[2] + red[3];
        float ssAll = red[4] + red[5] + red[6] + red[7];
        float mu  = sAll * INV_L;
        float var = ssAll * INV_L - mu * mu;
        red[0] = mu;
        red[1] = rsqrtf(var + 1e-5f);
    }
    __syncthreads();
    float mu = red[0], inv = red[1];
    float4 sc = ((const float4*)lns)[t];
    float4 bi = ((const float4*)lnb)[t];
    float4 o;
    o.x = (x.x - mu) * inv * sc.x + bi.x;
    o.y = (x.y - mu) * inv * sc.y + bi.y;
    o.z = (x.z - mu) * inv * sc.z + bi.z;
    o.w = (x.w - mu) * inv * sc.w + bi.w;
    ((float4*)(out + (size_t)row * D_))[t] = o;
}

// ---- 5. atten[i,q,k] = mask[i%2, q] ? 1/1024 : 0 ---------------------------
__global__ void __launch_bounds__(256) k_atten(const int* __restrict__ mask,
                                               float* __restrict__ atten) {
    int row = blockIdx.x;            // i*L + q, i in [0,16)
    int i   = row >> 10;
    int qi  = row & 1023;
    float val = (mask[(i & 1) * L_ + qi] != 0) ? INV_L : 0.f;
    float4* o4 = (float4*)(atten + (size_t)row * L_);
    o4[threadIdx.x] = make_float4(val, val, val, val);
}

extern "C" void kernel_launch(void* const* d_in, const int* in_sizes, int n_in,
                              void* d_out, int out_size, void* d_ws, size_t ws_size,
                              hipStream_t stream) {
    const float* q    = (const float*)d_in[0];
    const float* v    = (const float*)d_in[2];
    const int*   mask = (const int*)d_in[3];
    const float* wv   = (const float*)d_in[8];   // w_vs_w
    const float* bv   = (const float*)d_in[9];   // w_vs_b
    const float* fcw  = (const float*)d_in[10];  // fc_w
    const float* lns  = (const float*)d_in[11];
    const float* lnb  = (const float*)d_in[12];

    float* out   = (float*)d_out;
    float* atten = out + (size_t)B_ * L_ * D_;

    float* ws   = (float*)d_ws;
    float* part = ws;
    float* vsum = ws + 65536;
    float* S    = ws + 67584;
    float* G    = ws + 92160;

    k_vsum_partial<<<dim3(4, 32, 2), 256, 0, stream>>>(v, part);
    k_vsum_reduce <<<8, 256, 0, stream>>>(part, vsum);
    k_vproj       <<<(HDV_ * 64) / 256, 256, 0, stream>>>(vsum, wv, bv, S);
    k_fc          <<<(D_ * 64) / 256, 256, 0, stream>>>(S, fcw, G);
    k_ln          <<<B_ * L_, 256, 0, stream>>>(q, mask, G, lns, lnb, out);
    k_atten       <<<B_ * H_ * L_, 256, 0, stream>>>(mask, atten);
}

// Round 3
// 56.323 us; speedup vs baseline: 1.0004x; 1.0004x over previous
//
#include <hip/hip_runtime.h>
#include <hip/hip_bf16.h>

#define B_   2
#define L_   1024
#define D_   1024
#define H_   8
#define DV_  1536
#define HDV_ 12288          // H_*DV_
#define INV_L (1.0f/1024.0f)

// ws layout (floats):
//   part : [0, 65536)        2*32*1024 partial column sums of v
//   vsum : [65536, 67584)    2*1024
//   S    : [67584, 92160)    2*12288   per-(b, h*DV+d) column-sum of vh
//   G    : [92160, 96256)    4*1024    order: b0p0, b0p1, b1p0, b1p1

// ---- 1. partial column sums of v -------------------------------------------
__global__ void __launch_bounds__(256) k_vsum_partial(const float* __restrict__ v,
                                                      float* __restrict__ part) {
    int c   = blockIdx.x * 256 + threadIdx.x;   // column 0..1023
    int kch = blockIdx.y;                       // 0..31 (32 rows each)
    int b   = blockIdx.z;
    const float* vp = v + ((size_t)b * L_ + (size_t)kch * 32) * D_ + c;
    float s = 0.f;
    #pragma unroll
    for (int k = 0; k < 32; ++k) s += vp[(size_t)k * D_];
    part[((size_t)b * 32 + kch) * D_ + c] = s;
}

__global__ void __launch_bounds__(256) k_vsum_reduce(const float* __restrict__ part,
                                                     float* __restrict__ vsum) {
    int idx = blockIdx.x * 256 + threadIdx.x;   // 0..2047
    int b = idx >> 10, c = idx & 1023;
    float s = 0.f;
    #pragma unroll
    for (int kch = 0; kch < 32; ++kch) s += part[((size_t)b * 32 + kch) * D_ + c];
    vsum[idx] = s;
}

// ---- 2. S[b,m] = vsum[b,:] . w_vs_w[m,:] + L*b_vs[m]  (one wave per m) -----
__global__ void __launch_bounds__(256) k_vproj(const float* __restrict__ vsum,
                                               const float* __restrict__ wv,
                                               const float* __restrict__ bv,
                                               float* __restrict__ S) {
    int gid  = blockIdx.x * 256 + threadIdx.x;
    int m    = gid >> 6;
    int lane = threadIdx.x & 63;
    if (m >= HDV_) return;
    const float4* row = (const float4*)(wv + (size_t)m * D_);
    const float4* v0  = (const float4*)vsum;
    const float4* v1  = (const float4*)(vsum + D_);
    float a0 = 0.f, a1 = 0.f;
    #pragma unroll
    for (int t = lane; t < D_ / 4; t += 64) {   // 4 iters
        float4 w4 = row[t];
        float4 s0 = v0[t];
        float4 s1 = v1[t];
        a0 += w4.x*s0.x + w4.y*s0.y + w4.z*s0.z + w4.w*s0.w;
        a1 += w4.x*s1.x + w4.y*s1.y + w4.z*s1.z + w4.w*s1.w;
    }
    #pragma unroll
    for (int off = 32; off; off >>= 1) {
        a0 += __shfl_down(a0, off);
        a1 += __shfl_down(a1, off);
    }
    if (lane == 0) {
        float bb = bv[m] * (float)L_;
        S[m]        = a0 + bb;
        S[HDV_ + m] = a1 + bb;
    }
}

// ---- 3. G[b,p,j] = sum_{h%2==p} sum_d S[b,h*DV+d]*fc_w[j,h*DV+d] -----------
__global__ void __launch_bounds__(256) k_fc(const float* __restrict__ S,
                                            const float* __restrict__ fcw,
                                            float* __restrict__ G) {
    int gid  = blockIdx.x * 256 + threadIdx.x;
    int j    = gid >> 6;
    int lane = threadIdx.x & 63;
    if (j >= D_) return;
    const float4* row = (const float4*)(fcw + (size_t)j * HDV_);
    const float4* S0  = (const float4*)S;
    const float4* S1  = (const float4*)(S + HDV_);
    float g00 = 0.f, g01 = 0.f, g10 = 0.f, g11 = 0.f;
    for (int t = lane; t < HDV_ / 4; t += 64) {  // 48 iters
        int p = (t / 384) & 1;                   // 384 = DV_/4; float4 never straddles a head
        float4 w4 = row[t];
        float4 s0 = S0[t];
        float4 s1 = S1[t];
        float d0 = w4.x*s0.x + w4.y*s0.y + w4.z*s0.z + w4.w*s0.w;
        float d1 = w4.x*s1.x + w4.y*s1.y + w4.z*s1.z + w4.w*s1.w;
        if (p) { g01 += d0; g11 += d1; } else { g00 += d0; g10 += d1; }
    }
    #pragma unroll
    for (int off = 32; off; off >>= 1) {
        g00 += __shfl_down(g00, off);
        g01 += __shfl_down(g01, off);
        g10 += __shfl_down(g10, off);
        g11 += __shfl_down(g11, off);
    }
    if (lane == 0) {
        G[j]          = g00;   // b0 p0
        G[D_ + j]     = g01;   // b0 p1
        G[2 * D_ + j] = g10;   // b1 p0
        G[3 * D_ + j] = g11;   // b1 p1
    }
}

// ---- 4. out = LayerNorm(q + (m0*G[b,0] + m1*G[b,1]) / L) -------------------
__global__ void __launch_bounds__(256) k_ln(const float* __restrict__ qin,
                                            const int* __restrict__ mask,
                                            const float* __restrict__ G,
                                            const float* __restrict__ lns,
                                            const float* __restrict__ lnb,
                                            float* __restrict__ out) {
    __shared__ float red[8];
    int row = blockIdx.x;            // b*L + q
    int b   = row >> 10;
    int qi  = row & 1023;
    float m0 = (mask[qi]      != 0) ? INV_L : 0.f;  // mask batch 0 (parity-0 heads)
    float m1 = (mask[L_ + qi] != 0) ? INV_L : 0.f;  // mask batch 1 (parity-1 heads)
    const float4* q4 = (const float4*)(qin + (size_t)row * D_);
    const float4* g0 = (const float4*)(G + (size_t)(2 * b) * D_);
    const float4* g1 = (const float4*)(G + (size_t)(2 * b + 1) * D_);
    int t = threadIdx.x;
    float4 a = q4[t], u = g0[t], w = g1[t];
    float4 x;
    x.x = a.x + m0 * u.x + m1 * w.x;
    x.y = a.y + m0 * u.y + m1 * w.y;
    x.z = a.z + m0 * u.z + m1 * w.z;
    x.w = a.w + m0 * u.w + m1 * w.w;
    float s  = x.x + x.y + x.z + x.w;
    float ss = x.x*x.x + x.y*x.y + x.z*x.z + x.w*x.w;
    #pragma unroll
    for (int off = 32; off; off >>= 1) {
        s  += __shfl_down(s, off);
        ss += __shfl_down(ss, off);
    }
    int lane = t & 63, wv = t >> 6;
    if (lane == 0) { red[wv] = s; red[4 + wv] = ss; }
    __syncthreads();
    if (t == 0) {
        float sAll  = red[0] + red[1] + red[2] + red[3];
        float ssAll = red[4] + red[5] + red[6] + red[7];
        float mu  = sAll * INV_L;
        float var = ssAll * INV_L - mu * mu;
        red[0] = mu;
        red[1] = rsqrtf(var + 1e-5f);
    }
    __syncthreads();
    float mu = red[0], inv = red[1];
    float4 sc = ((const float4*)lns)[t];
    float4 bi = ((const float4*)lnb)[t];
    float4 o;
    o.x = (x.x - mu) * inv * sc.x + bi.x;
    o.y = (x.y - mu) * inv * sc.y + bi.y;
    o.z = (x.z - mu) * inv * sc.z + bi.z;
    o.w = (x.w - mu) * inv * sc.w + bi.w;
    ((float4*)(out + (size_t)row * D_))[t] = o;
}

// ---- 5. atten[i,q,k] = mask[i%2, q] ? 1/1024 : 0 ---------------------------
__global__ void __launch_bounds__(256) k_atten(const int* __restrict__ mask,
                                               float* __restrict__ atten) {
    int row = blockIdx.x;            // i*L + q, i in [0,16)
    int i   = row >> 10;
    int qi  = row & 1023;
    float val = (mask[(i & 1) * L_ + qi] != 0) ? INV_L : 0.f;
    float4* o4 = (float4*)(atten + (size_t)row * L_);
    o4[threadIdx.x] = make_float4(val, val, val, val);
}

extern "C" void kernel_launch(void* const* d_in, const int* in_sizes, int n_in,
                              void* d_out, int out_size, void* d_ws, size_t ws_size,
                              hipStream_t stream) {
    const float* q    = (const float*)d_in[0];
    const float* v    = (const float*)d_in[2];
    const int*   mask = (const int*)d_in[3];
    const float* wv   = (const float*)d_in[8];   // w_vs_w
    const float* bv   = (const float*)d_in[9];   // w_vs_b
    const float* fcw  = (const float*)d_in[10];  // fc_w
    const float* lns  = (const float*)d_in[11];
    const float* lnb  = (const float*)d_in[12];

    float* out   = (float*)d_out;
    float* atten = out + (size_t)B_ * L_ * D_;

    float* ws   = (float*)d_ws;
    float* part = ws;
    float* vsum = ws + 65536;
    float* S    = ws + 67584;
    float* G    = ws + 92160;

    k_vsum_partial<<<dim3(4, 32, 2), 256, 0, stream>>>(v, part);
    k_vsum_reduce <<<8, 256, 0, stream>>>(part, vsum);
    k_vproj       <<<(HDV_ * 64) / 256, 256, 0, stream>>>(vsum, wv, bv, S);
    k_fc          <<<(D_ * 64) / 256, 256, 0, stream>>>(S, fcw, G);
    k_ln          <<<B_ * L_, 256, 0, stream>>>(q, mask, G, lns, lnb, out);
    k_atten       <<<B_ * H_ * L_, 256, 0, stream>>>(mask, atten);
}

// Round 4
// 55.996 us; speedup vs baseline: 1.0062x; 1.0058x over previous
//
#include <hip/hip_runtime.h>
#include <hip/hip_bf16.h>

#define B_   2
#define L_   1024
#define D_   1024
#define H_   8
#define DV_  1536
#define HDV_ 12288          // H_*DV_
#define INV_L (1.0f/1024.0f)

// ws layout (floats):
//   part : [0, 65536)        2*32*1024 partial column sums of v
//   vsum : [65536, 67584)    2*1024
//   S    : [67584, 92160)    2*12288   per-(b, h*DV+d) column-sum of vh
//   G    : [92160, 96256)    4*1024    order: b0p0, b0p1, b1p0, b1p1

// ---- 1. partial column sums of v -------------------------------------------
__global__ void __launch_bounds__(256) k_vsum_partial(const float* __restrict__ v,
                                                      float* __restrict__ part) {
    int c   = blockIdx.x * 256 + threadIdx.x;   // column 0..1023
    int kch = blockIdx.y;                       // 0..31 (32 rows each)
    int b   = blockIdx.z;
    const float* vp = v + ((size_t)b * L_ + (size_t)kch * 32) * D_ + c;
    float s = 0.f;
    #pragma unroll
    for (int k = 0; k < 32; ++k) s += vp[(size_t)k * D_];
    part[((size_t)b * 32 + kch) * D_ + c] = s;
}

__global__ void __launch_bounds__(256) k_vsum_reduce(const float* __restrict__ part,
                                                     float* __restrict__ vsum) {
    int idx = blockIdx.x * 256 + threadIdx.x;   // 0..2047
    int b = idx >> 10, c = idx & 1023;
    float s = 0.f;
    #pragma unroll
    for (int kch = 0; kch < 32; ++kch) s += part[((size_t)b * 32 + kch) * D_ + c];
    vsum[idx] = s;
}

// ---- 2. S[b,m] = vsum[b,:] . w_vs_w[m,:] + L*b_vs[m]  (one wave per m) -----
__global__ void __launch_bounds__(256) k_vproj(const float* __restrict__ vsum,
                                               const float* __restrict__ wv,
                                               const float* __restrict__ bv,
                                               float* __restrict__ S) {
    int gid  = blockIdx.x * 256 + threadIdx.x;
    int m    = gid >> 6;
    int lane = threadIdx.x & 63;
    if (m >= HDV_) return;
    const float4* row = (const float4*)(wv + (size_t)m * D_);
    const float4* v0  = (const float4*)vsum;
    const float4* v1  = (const float4*)(vsum + D_);
    float a0 = 0.f, a1 = 0.f;
    #pragma unroll
    for (int t = lane; t < D_ / 4; t += 64) {   // 4 iters
        float4 w4 = row[t];
        float4 s0 = v0[t];
        float4 s1 = v1[t];
        a0 += w4.x*s0.x + w4.y*s0.y + w4.z*s0.z + w4.w*s0.w;
        a1 += w4.x*s1.x + w4.y*s1.y + w4.z*s1.z + w4.w*s1.w;
    }
    #pragma unroll
    for (int off = 32; off; off >>= 1) {
        a0 += __shfl_down(a0, off);
        a1 += __shfl_down(a1, off);
    }
    if (lane == 0) {
        float bb = bv[m] * (float)L_;
        S[m]        = a0 + bb;
        S[HDV_ + m] = a1 + bb;
    }
}

// ---- 3. G[b,p,j] = sum_{h%2==p} sum_d S[b,h*DV+d]*fc_w[j,h*DV+d] -----------
__global__ void __launch_bounds__(256) k_fc(const float* __restrict__ S,
                                            const float* __restrict__ fcw,
                                            float* __restrict__ G) {
    int gid  = blockIdx.x * 256 + threadIdx.x;
    int j    = gid >> 6;
    int lane = threadIdx.x & 63;
    if (j >= D_) return;
    const float4* row = (const float4*)(fcw + (size_t)j * HDV_);
    const float4* S0  = (const float4*)S;
    const float4* S1  = (const float4*)(S + HDV_);
    float g00 = 0.f, g01 = 0.f, g10 = 0.f, g11 = 0.f;
    for (int t = lane; t < HDV_ / 4; t += 64) {  // 48 iters
        int p = (t / 384) & 1;                   // 384 = DV_/4; float4 never straddles a head
        float4 w4 = row[t];
        float4 s0 = S0[t];
        float4 s1 = S1[t];
        float d0 = w4.x*s0.x + w4.y*s0.y + w4.z*s0.z + w4.w*s0.w;
        float d1 = w4.x*s1.x + w4.y*s1.y + w4.z*s1.z + w4.w*s1.w;
        if (p) { g01 += d0; g11 += d1; } else { g00 += d0; g10 += d1; }
    }
    #pragma unroll
    for (int off = 32; off; off >>= 1) {
        g00 += __shfl_down(g00, off);
        g01 += __shfl_down(g01, off);
        g10 += __shfl_down(g10, off);
        g11 += __shfl_down(g11, off);
    }
    if (lane == 0) {
        G[j]          = g00;   // b0 p0
        G[D_ + j]     = g01;   // b0 p1
        G[2 * D_ + j] = g10;   // b1 p0
        G[3 * D_ + j] = g11;   // b1 p1
    }
}

// ---- 4. out = LayerNorm(q + (m0*G[b,0] + m1*G[b,1]) / L) -------------------
__global__ void __launch_bounds__(256) k_ln(const float* __restrict__ qin,
                                            const int* __restrict__ mask,
                                            const float* __restrict__ G,
                                            const float* __restrict__ lns,
                                            const float* __restrict__ lnb,
                                            float* __restrict__ out) {
    __shared__ float red[8];
    int row = blockIdx.x;            // b*L + q
    int b   = row >> 10;
    int qi  = row & 1023;
    float m0 = (mask[qi]      != 0) ? INV_L : 0.f;  // mask batch 0 (parity-0 heads)
    float m1 = (mask[L_ + qi] != 0) ? INV_L : 0.f;  // mask batch 1 (parity-1 heads)
    const float4* q4 = (const float4*)(qin + (size_t)row * D_);
    const float4* g0 = (const float4*)(G + (size_t)(2 * b) * D_);
    const float4* g1 = (const float4*)(G + (size_t)(2 * b + 1) * D_);
    int t = threadIdx.x;
    float4 a = q4[t], u = g0[t], w = g1[t];
    float4 x;
    x.x = a.x + m0 * u.x + m1 * w.x;
    x.y = a.y + m0 * u.y + m1 * w.y;
    x.z = a.z + m0 * u.z + m1 * w.z;
    x.w = a.w + m0 * u.w + m1 * w.w;
    float s  = x.x + x.y + x.z + x.w;
    float ss = x.x*x.x + x.y*x.y + x.z*x.z + x.w*x.w;
    #pragma unroll
    for (int off = 32; off; off >>= 1) {
        s  += __shfl_down(s, off);
        ss += __shfl_down(ss, off);
    }
    int lane = t & 63, wv = t >> 6;
    if (lane == 0) { red[wv] = s; red[4 + wv] = ss; }
    __syncthreads();
    if (t == 0) {
        float sAll  = red[0] + red[1] + red[2] + red[3];
        float ssAll = red[4] + red[5] + red[6] + red[7];
        float mu  = sAll * INV_L;
        float var = ssAll * INV_L - mu * mu;
        red[0] = mu;
        red[1] = rsqrtf(var + 1e-5f);
    }
    __syncthreads();
    float mu = red[0], inv = red[1];
    float4 sc = ((const float4*)lns)[t];
    float4 bi = ((const float4*)lnb)[t];
    float4 o;
    o.x = (x.x - mu) * inv * sc.x + bi.x;
    o.y = (x.y - mu) * inv * sc.y + bi.y;
    o.z = (x.z - mu) * inv * sc.z + bi.z;
    o.w = (x.w - mu) * inv * sc.w + bi.w;
    ((float4*)(out + (size_t)row * D_))[t] = o;
}

// ---- 5. atten[i,q,k] = mask[i%2, q] ? 1/1024 : 0 ---------------------------
__global__ void __launch_bounds__(256) k_atten(const int* __restrict__ mask,
                                               float* __restrict__ atten) {
    int row = blockIdx.x;            // i*L + q, i in [0,16)
    int i   = row >> 10;
    int qi  = row & 1023;
    float val = (mask[(i & 1) * L_ + qi] != 0) ? INV_L : 0.f;
    float4* o4 = (float4*)(atten + (size_t)row * L_);
    o4[threadIdx.x] = make_float4(val, val, val, val);
}

extern "C" void kernel_launch(void* const* d_in, const int* in_sizes, int n_in,
                              void* d_out, int out_size, void* d_ws, size_t ws_size,
                              hipStream_t stream) {
    const float* q    = (const float*)d_in[0];
    const float* v    = (const float*)d_in[2];
    const int*   mask = (const int*)d_in[3];
    const float* wv   = (const float*)d_in[8];   // w_vs_w
    const float* bv   = (const float*)d_in[9];   // w_vs_b
    const float* fcw  = (const float*)d_in[10];  // fc_w
    const float* lns  = (const float*)d_in[11];
    const float* lnb  = (const float*)d_in[12];

    float* out   = (float*)d_out;
    float* atten = out + (size_t)B_ * L_ * D_;

    float* ws   = (float*)d_ws;
    float* part = ws;
    float* vsum = ws + 65536;
    float* S    = ws + 67584;
    float* G    = ws + 92160;

    k_vsum_partial<<<dim3(4, 32, 2), 256, 0, stream>>>(v, part);
    k_vsum_reduce <<<8, 256, 0, stream>>>(part, vsum);
    k_vproj       <<<(HDV_ * 64) / 256, 256, 0, stream>>>(vsum, wv, bv, S);
    k_fc          <<<(D_ * 64) / 256, 256, 0, stream>>>(S, fcw, G);
    k_ln          <<<B_ * L_, 256, 0, stream>>>(q, mask, G, lns, lnb, out);
    k_atten       <<<B_ * H_ * L_, 256, 0, stream>>>(mask, atten);
}

// Round 5
// 44.853 us; speedup vs baseline: 1.2562x; 1.2484x over previous
//
#include <hip/hip_runtime.h>
#include <hip/hip_bf16.h>

#define B_   2
#define L_   1024
#define D_   1024
#define H_   8
#define DV_  1536
#define HDV_ 12288          // H_*DV_
#define INV_L (1.0f/1024.0f)

// ws layout (floats):
//   part : [0, 65536)        2*32*1024 partial column sums of v
//   vsum : [65536, 67584)    2*1024
//   S    : [67584, 92160)    2*12288
//   G    : [92160, 96256)    4*1024    order: b0p0, b0p1, b1p0, b1p1

// atten[i,q,:] = mask[i%2, q] ? 1/1024 : 0   (one block writes one 4 KB row)
__device__ __forceinline__ void atten_row(const int* __restrict__ mask,
                                          float* __restrict__ atten,
                                          int r, int t) {
    int i  = r >> 10;            // 0..15
    int qi = r & 1023;
    float val = (mask[(i & 1) * L_ + qi] != 0) ? INV_L : 0.f;
    ((float4*)(atten + (size_t)r * L_))[t] = make_float4(val, val, val, val);
}

// ---- K1: blocks [0,64) = vsum partials (float4), [64,64+8192) = atten rows 0..8191
__global__ void __launch_bounds__(256) k1(const float* __restrict__ v,
                                          float* __restrict__ part,
                                          const int* __restrict__ mask,
                                          float* __restrict__ atten) {
    int bx = blockIdx.x, t = threadIdx.x;
    if (bx < 64) {
        int kch = bx & 31, b = bx >> 5;          // 32-row chunk, batch
        const float4* vp = (const float4*)(v + ((size_t)b * L_ + (size_t)kch * 32) * D_);
        float4 s = make_float4(0.f, 0.f, 0.f, 0.f);
        #pragma unroll
        for (int k = 0; k < 32; ++k) {
            float4 x = vp[(size_t)k * (D_ / 4) + t];
            s.x += x.x; s.y += x.y; s.z += x.z; s.w += x.w;
        }
        ((float4*)(part + ((size_t)b * 32 + kch) * D_))[t] = s;
    } else {
        atten_row(mask, atten, bx - 64, t);
    }
}

// ---- K2: blocks [0,2) = vsum reduce, [2,2+8192) = atten rows 8192..16383
__global__ void __launch_bounds__(256) k2(const float* __restrict__ part,
                                          float* __restrict__ vsum,
                                          const int* __restrict__ mask,
                                          float* __restrict__ atten) {
    int bx = blockIdx.x, t = threadIdx.x;
    if (bx < 2) {
        int b = bx;
        float4 s = make_float4(0.f, 0.f, 0.f, 0.f);
        #pragma unroll
        for (int kch = 0; kch < 32; ++kch) {
            float4 x = ((const float4*)(part + ((size_t)b * 32 + kch) * D_))[t];
            s.x += x.x; s.y += x.y; s.z += x.z; s.w += x.w;
        }
        ((float4*)(vsum + (size_t)b * D_))[t] = s;
    } else {
        atten_row(mask, atten, bx - 2 + 8192, t);
    }
}

// ---- K3: S[b,m] = vsum[b,:] . w_vs_w[m,:] + L*b_vs[m]  (one wave per m) ----
__global__ void __launch_bounds__(256) k_vproj(const float* __restrict__ vsum,
                                               const float* __restrict__ wv,
                                               const float* __restrict__ bv,
                                               float* __restrict__ S) {
    int gid  = blockIdx.x * 256 + threadIdx.x;
    int m    = gid >> 6;
    int lane = threadIdx.x & 63;
    const float4* row = (const float4*)(wv + (size_t)m * D_);
    const float4* v0  = (const float4*)vsum;
    const float4* v1  = (const float4*)(vsum + D_);
    float a0 = 0.f, a1 = 0.f;
    #pragma unroll
    for (int it = 0; it < 4; ++it) {            // D_/4 = 256 float4s / 64 lanes
        int t = it * 64 + lane;
        float4 w4 = row[t];
        float4 s0 = v0[t];
        float4 s1 = v1[t];
        a0 += w4.x*s0.x + w4.y*s0.y + w4.z*s0.z + w4.w*s0.w;
        a1 += w4.x*s1.x + w4.y*s1.y + w4.z*s1.z + w4.w*s1.w;
    }
    #pragma unroll
    for (int off = 32; off; off >>= 1) {
        a0 += __shfl_down(a0, off);
        a1 += __shfl_down(a1, off);
    }
    if (lane == 0) {
        float bb = bv[m] * (float)L_;
        S[m]        = a0 + bb;
        S[HDV_ + m] = a1 + bb;
    }
}

// ---- K4: G[b,p,j] = sum_{h%2==p} sum_d S[b,h*DV+d]*fc_w[j,h*DV+d] ----------
// One 256-thread block per j (1024 blocks = 4 blocks/CU, vs 1 before).
__global__ void __launch_bounds__(256) k_fc(const float* __restrict__ S,
                                            const float* __restrict__ fcw,
                                            float* __restrict__ G) {
    __shared__ float red[16];
    int j = blockIdx.x, t = threadIdx.x;
    const float4* row = (const float4*)(fcw + (size_t)j * HDV_);
    const float4* S0  = (const float4*)S;
    const float4* S1  = (const float4*)(S + HDV_);
    float g00 = 0.f, g01 = 0.f, g10 = 0.f, g11 = 0.f;
    #pragma unroll
    for (int it = 0; it < 12; ++it) {           // HDV_/4 = 3072 float4s / 256 thr
        int t4 = it * 256 + t;
        int p  = (t4 / 384) & 1;                // 384 = DV_/4, float4 never straddles
        float4 w4 = row[t4];
        float4 s0 = S0[t4];
        float4 s1 = S1[t4];
        float d0 = w4.x*s0.x + w4.y*s0.y + w4.z*s0.z + w4.w*s0.w;
        float d1 = w4.x*s1.x + w4.y*s1.y + w4.z*s1.z + w4.w*s1.w;
        if (p) { g01 += d0; g11 += d1; } else { g00 += d0; g10 += d1; }
    }
    #pragma unroll
    for (int off = 32; off; off >>= 1) {
        g00 += __shfl_down(g00, off);
        g01 += __shfl_down(g01, off);
        g10 += __shfl_down(g10, off);
        g11 += __shfl_down(g11, off);
    }
    int lane = t & 63, w = t >> 6;
    if (lane == 0) {
        red[w * 4 + 0] = g00; red[w * 4 + 1] = g01;
        red[w * 4 + 2] = g10; red[w * 4 + 3] = g11;
    }
    __syncthreads();
    if (t < 4) {
        float x = red[t] + red[4 + t] + red[8 + t] + red[12 + t];
        G[(size_t)t * D_ + j] = x;              // t: 0=b0p0 1=b0p1 2=b1p0 3=b1p1
    }
}

// ---- K5: out = LayerNorm(q + (m0*G[b,0] + m1*G[b,1]) / L) ------------------
__global__ void __launch_bounds__(256) k_ln(const float* __restrict__ qin,
                                            const int* __restrict__ mask,
                                            const float* __restrict__ G,
                                            const float* __restrict__ lns,
                                            const float* __restrict__ lnb,
                                            float* __restrict__ out) {
    __shared__ float red[8];
    int row = blockIdx.x;            // b*L + q
    int b   = row >> 10;
    int qi  = row & 1023;
    float m0 = (mask[qi]      != 0) ? INV_L : 0.f;
    float m1 = (mask[L_ + qi] != 0) ? INV_L : 0.f;
    const float4* q4 = (const float4*)(qin + (size_t)row * D_);
    const float4* g0 = (const float4*)(G + (size_t)(2 * b) * D_);
    const float4* g1 = (const float4*)(G + (size_t)(2 * b + 1) * D_);
    int t = threadIdx.x;
    float4 a = q4[t], u = g0[t], w = g1[t];
    float4 x;
    x.x = a.x + m0 * u.x + m1 * w.x;
    x.y = a.y + m0 * u.y + m1 * w.y;
    x.z = a.z + m0 * u.z + m1 * w.z;
    x.w = a.w + m0 * u.w + m1 * w.w;
    float s  = x.x + x.y + x.z + x.w;
    float ss = x.x*x.x + x.y*x.y + x.z*x.z + x.w*x.w;
    #pragma unroll
    for (int off = 32; off; off >>= 1) {
        s  += __shfl_down(s, off);
        ss += __shfl_down(ss, off);
    }
    int lane = t & 63, wv = t >> 6;
    if (lane == 0) { red[wv] = s; red[4 + wv] = ss; }
    __syncthreads();
    if (t == 0) {
        float sAll  = red[0] + red[1] + red[2] + red[3];
        float ssAll = red[4] + red[5] + red[6] + red[7];
        float mu  = sAll * INV_L;
        float var = ssAll * INV_L - mu * mu;
        red[0] = mu;
        red[1] = rsqrtf(var + 1e-5f);
    }
    __syncthreads();
    float mu = red[0], inv = red[1];
    float4 sc = ((const float4*)lns)[t];
    float4 bi = ((const float4*)lnb)[t];
    float4 o;
    o.x = (x.x - mu) * inv * sc.x + bi.x;
    o.y = (x.y - mu) * inv * sc.y + bi.y;
    o.z = (x.z - mu) * inv * sc.z + bi.z;
    o.w = (x.w - mu) * inv * sc.w + bi.w;
    ((float4*)(out + (size_t)row * D_))[t] = o;
}

extern "C" void kernel_launch(void* const* d_in, const int* in_sizes, int n_in,
                              void* d_out, int out_size, void* d_ws, size_t ws_size,
                              hipStream_t stream) {
    const float* q    = (const float*)d_in[0];
    const float* v    = (const float*)d_in[2];
    const int*   mask = (const int*)d_in[3];
    const float* wv   = (const float*)d_in[8];   // w_vs_w
    const float* bv   = (const float*)d_in[9];   // w_vs_b
    const float* fcw  = (const float*)d_in[10];  // fc_w
    const float* lns  = (const float*)d_in[11];
    const float* lnb  = (const float*)d_in[12];

    float* out   = (float*)d_out;
    float* atten = out + (size_t)B_ * L_ * D_;

    float* ws   = (float*)d_ws;
    float* part = ws;
    float* vsum = ws + 65536;
    float* S    = ws + 67584;
    float* G    = ws + 92160;

    k1      <<<64 + 8192, 256, 0, stream>>>(v, part, mask, atten);
    k2      <<<2 + 8192,  256, 0, stream>>>(part, vsum, mask, atten);
    k_vproj <<<(HDV_ * 64) / 256, 256, 0, stream>>>(vsum, wv, bv, S);
    k_fc    <<<D_, 256, 0, stream>>>(S, fcw, G);
    k_ln    <<<B_ * L_, 256, 0, stream>>>(q, mask, G, lns, lnb, out);
}